// Round 11
// baseline (176.307 us; speedup 1.0000x reference)
//
#include <hip/hip_runtime.h>
#include <hip/hip_bf16.h>

#define F 128
#define RANGES 8
#define SLICES 64
#define GROUPS 4
#define GSL 16   // slices per group

typedef unsigned int u32;
typedef unsigned short u16;
typedef __attribute__((ext_vector_type(8))) short short8;   // bf16x8 MFMA frag
typedef __attribute__((ext_vector_type(4))) float f32x4;    // MFMA acc

__device__ __forceinline__ u16 f2bf(float x) {
    u32 u = __float_as_uint(x);
    u32 r = u + 0x7fffu + ((u >> 16) & 1u);   // RNE
    return (u16)(r >> 16);
}

// ---------------- range-partitioned LDS histogram + per-edge rank, no global atomics ----------------
__global__ __launch_bounds__(256) void hist_kernel(const int* __restrict__ src,
                                                   const int* __restrict__ dst,
                                                   u32* __restrict__ rep,
                                                   u16* __restrict__ eRank,
                                                   int E, int n, int rsize, int eps) {
    int r = blockIdx.x & (RANGES - 1);
    int s = blockIdx.x / RANGES;
    int lo = r * rsize;
    int hi = lo + rsize; if (hi > n) hi = n;
    int len = hi - lo;                 // 6250
    int words = (len + 1) >> 1;        // 3125
    __shared__ u32 h0[3200], h1[3200]; // 25.6 KB total
    for (int i = threadIdx.x; i < 3200; i += 256) { h0[i] = 0; h1[i] = 0; }
    __syncthreads();
    int e0 = s * eps, e1 = e0 + eps; if (e1 > E) e1 = E;
    for (int e = e0 + threadIdx.x; e < e1; e += 256) {
        int a = src[e] - lo;
        if ((u32)a < (u32)len) atomicAdd(&h0[a >> 1], 1u << ((a & 1) * 16));
        int b = dst[e] - lo;
        if ((u32)b < (u32)len) {
            int sh = (b & 1) * 16;
            u32 old = atomicAdd(&h1[b >> 1], 1u << sh);
            eRank[e] = (u16)((old >> sh) & 0xffffu);
        }
    }
    __syncthreads();
    int nw = n >> 1;
    u32* ro = rep + (size_t)s * 2 * nw + (lo >> 1);
    for (int i = threadIdx.x; i < words; i += 256) {
        ro[i]      = h0[i];
        ro[nw + i] = h1[i];
    }
}

// ---------------- per-group slice sums (packed) + per-(b,g) bsum partial (no atomics) ----------------
__global__ void slicesum_kernel(const u32* __restrict__ rep, u32* __restrict__ gout,
                                u32* __restrict__ gin, int* __restrict__ bsum2, int nw) {
    int b = blockIdx.x >> 2;
    int g = blockIdx.x & 3;
    int t = threadIdx.x;
    int j = b * 256 + t;
    u32 so = 0, si = 0;
    if (j < nw) {
        const u32* base = rep + (size_t)(g * GSL) * 2 * nw;
        #pragma unroll 4
        for (int s = 0; s < GSL; s++) {
            so += base[(size_t)s * 2 * nw + j];
            si += base[(size_t)s * 2 * nw + nw + j];
        }
        gout[g * nw + j] = so;
        gin [g * nw + j] = si;
    }
    int tot = (int)(si & 0xffffu) + (int)(si >> 16);
    for (int off = 32; off > 0; off >>= 1) tot += __shfl_down(tot, off, 64);
    __shared__ int ws[4];
    if ((t & 63) == 0) ws[t >> 6] = tot;
    __syncthreads();
    if (t == 0) bsum2[b * GROUPS + g] = ws[0] + ws[1] + ws[2] + ws[3];
}

// ---------------- exclusive scan of block sums (nb <= 256), folds 4 group partials ----------------
__global__ void scan_bsum_kernel(const int* __restrict__ bsum2, int* __restrict__ bsum,
                                 u32* __restrict__ row_start, int nb, int n) {
    __shared__ int sh[256];
    int t = threadIdx.x;
    int x = 0;
    if (t < nb) {
        #pragma unroll
        for (int g = 0; g < GROUPS; g++) x += bsum2[t * GROUPS + g];
    }
    sh[t] = x;
    __syncthreads();
    for (int off = 1; off < 256; off <<= 1) {
        int y = (t >= off) ? sh[t - off] : 0;
        __syncthreads();
        sh[t] += y;
        __syncthreads();
    }
    if (t < nb) bsum[t] = sh[t] - x;
    if (t == 255) row_start[n] = (u32)sh[255];
}

// ---------------- full exclusive scan -> row_start ----------------
__global__ void scan_final_kernel(const u32* __restrict__ gin, const int* __restrict__ bsum,
                                  u32* __restrict__ row_start, int n, int nw) {
    int t = threadIdx.x, lane = t & 63, wid = t >> 6;
    int j = blockIdx.x * 256 + t;
    u32 v0 = 0, v1 = 0;
    if (j < nw) {
        #pragma unroll
        for (int g = 0; g < GROUPS; g++) {
            u32 w = gin[g * nw + j];
            v0 += w & 0xffffu; v1 += w >> 16;
        }
    }
    int sum2 = (int)(v0 + v1);
    int x = sum2;
    for (int off = 1; off < 64; off <<= 1) {
        int y = __shfl_up(x, off, 64);
        if (lane >= off) x += y;
    }
    int wex = x - sum2;
    __shared__ int wtot[4];
    if (lane == 63) wtot[wid] = x;
    __syncthreads();
    int wbase = 0;
    for (int w = 0; w < wid; w++) wbase += wtot[w];
    int base = bsum[blockIdx.x] + wbase + wex;
    if (j < nw) {
        uint2 rs; rs.x = (u32)base; rs.y = (u32)base + v0;
        *(uint2*)&row_start[2 * j] = rs;
    }
}

// ---------------- prep: cursorw (blocks 0..391) | xconv (392..6641) | wconv (6642..6705) ----------------
__global__ void prep_kernel(const u32* __restrict__ rep, const u32* __restrict__ gin,
                            const u32* __restrict__ row_start, u32* __restrict__ cursor_base,
                            const float4* __restrict__ feat4, const u32* __restrict__ gout,
                            ushort4* __restrict__ xb4,
                            const float* __restrict__ Wg, u16* __restrict__ wsw,
                            int n, int nw, int total) {
    int bid = blockIdx.x;
    int t = threadIdx.x;
    if (bid < 392) {
        // -------- cursorw --------
        int b = bid >> 2;
        int g = bid & 3;
        int j = b * 256 + t;
        if (j >= nw) return;
        int i0 = 2 * j;
        uint2 rs = *(const uint2*)&row_start[i0];
        u32 c0 = rs.x, c1 = rs.y;
        for (int gp = 0; gp < g; gp++) {
            u32 w = gin[gp * nw + j];
            c0 += w & 0xffffu; c1 += w >> 16;
        }
        const u32* rin = rep + (size_t)(g * GSL) * 2 * nw + nw;
        u32* cb = cursor_base + (size_t)(g * GSL) * n + i0;
        #pragma unroll 4
        for (int s = 0; s < GSL; s++) {
            uint2 cc; cc.x = c0; cc.y = c1;
            *(uint2*)cb = cc;
            u32 w = rin[(size_t)s * 2 * nw + j];
            c0 += w & 0xffffu; c1 += w >> 16;
            cb += n;
        }
    } else if (bid < 6642) {
        // -------- xconv --------
        int i = (bid - 392) * 256 + t;
        if (i >= total) return;
        int row = i >> 5;
        int j = row >> 1, sh = (row & 1) * 16;
        u32 dg = 0;
        #pragma unroll
        for (int g = 0; g < GROUPS; g++) dg += (gout[g * nw + j] >> sh) & 0xffffu;
        if (dg < 1u) dg = 1u;
        float ns = rsqrtf((float)dg);
        float4 v = feat4[i];
        ushort4 o;
        o.x = f2bf(v.x * ns); o.y = f2bf(v.y * ns);
        o.z = f2bf(v.z * ns); o.w = f2bf(v.w * ns);
        xb4[i] = o;
    } else {
        // -------- wconv --------
        int i = (bid - 6642) * 256 + t;   // 0..16383
        int k = i >> 7, col = i & 127;
        u16 h = f2bf(Wg[i]);
        wsw[col * 128 + 8 * ((k >> 3) ^ (col & 15)) + (k & 7)] = h;
    }
}

// ---------------- placement: fully deterministic, zero atomics ----------------
__global__ void place_kernel(const int* __restrict__ src, const int* __restrict__ dst,
                             const u16* __restrict__ eRank, const u32* __restrict__ cursor_base,
                             int* __restrict__ eidx, int E, int n, int eps) {
    int e = blockIdx.x * blockDim.x + threadIdx.x;
    if (e < E) {
        int d = dst[e];
        int s = e / eps;
        u32 pos = cursor_base[(size_t)s * n + d] + eRank[e];
        eidx[pos] = src[e];
    }
}

// ---------------- fused gather + gemm: tile rows gathered into LDS, then MFMA ----------------
// Each block owns 64 output rows; wave wv gathers rows wv*16..+15 into padded LDS
// (stride 68 words -> 2-way banks), then computes the same rows' MFMA output.
#define BM 64
__launch_bounds__(256)
__global__ void gather_gemm_kernel(const u32* __restrict__ xb32, const int* __restrict__ eidx,
                                   const u32* __restrict__ row_start, const u32* __restrict__ gin,
                                   const uint4* __restrict__ wsw4, const float* __restrict__ bias,
                                   float* __restrict__ out, int n, int nw) {
    __shared__ uint4 WL[2048];    // 32 KB swizzled W
    __shared__ u32 AL[BM * 68];   // 17 KB padded A tile (row stride 272 B)
    int t = threadIdx.x;
    for (int j = t; j < 2048; j += 256)
        WL[j] = wsw4[j];

    int lane = t & 63;
    int wv = t >> 6;
    int rowBase = blockIdx.x * BM;

    // gather this wave's 16 rows
    for (int i = 0; i < 16; i++) {
        int d = rowBase + wv * 16 + i;
        float ax = 0.f, ay = 0.f;
        if (d < n) {
            int beg = (int)row_start[d], end = (int)row_start[d + 1];
            int k = beg;
            for (; k + 8 <= end; k += 8) {
                u32 v[8];
                #pragma unroll
                for (int q = 0; q < 8; q++) {
                    int sq = __builtin_amdgcn_readfirstlane(eidx[k + q]);
                    v[q] = xb32[(size_t)sq * 64 + lane];
                }
                #pragma unroll
                for (int q = 0; q < 8; q++) {
                    ax += __uint_as_float(v[q] << 16);
                    ay += __uint_as_float(v[q] & 0xffff0000u);
                }
            }
            for (; k < end; k++) {
                int s0 = __builtin_amdgcn_readfirstlane(eidx[k]);
                u32 v0 = xb32[(size_t)s0 * 64 + lane];
                ax += __uint_as_float(v0 << 16);
                ay += __uint_as_float(v0 & 0xffff0000u);
            }
            int j = d >> 1, sh = (d & 1) * 16;
            u32 dg = 0;
            #pragma unroll
            for (int g = 0; g < GROUPS; g++) dg += (gin[g * nw + j] >> sh) & 0xffffu;
            if (dg < 1u) dg = 1u;
            float nd = rsqrtf((float)dg);
            ax *= nd; ay *= nd;
        }
        u32 lo = (u32)f2bf(ax), hi = (u32)f2bf(ay);
        AL[(wv * 16 + i) * 68 + lane] = lo | (hi << 16);
    }
    __syncthreads();   // WL staged by all, AL rows complete

    int g = lane >> 4;
    int c15 = lane & 15;

    f32x4 acc[8];
    #pragma unroll
    for (int nf = 0; nf < 8; nf++) acc[nf] = (f32x4){0.f, 0.f, 0.f, 0.f};

    #pragma unroll
    for (int kk = 0; kk < 4; kk++) {
        int G = 4 * kk + g;
        short8 a = *(const short8*)&AL[(wv * 16 + c15) * 68 + G * 4];
        int sg = G ^ c15;
        #pragma unroll
        for (int nf = 0; nf < 8; nf++) {
            int col = c15 + 16 * nf;
            short8 b = ((const short8*)WL)[col * 16 + sg];
            acc[nf] = __builtin_amdgcn_mfma_f32_16x16x32_bf16(a, b, acc[nf], 0, 0, 0);
        }
    }

    int rbase = rowBase + wv * 16 + g * 4;   // D: row=(lane>>4)*4+r, col=lane&15 (+16nf)
    #pragma unroll
    for (int nf = 0; nf < 8; nf++) {
        int col = c15 + 16 * nf;
        float bv = bias[col];
        #pragma unroll
        for (int r = 0; r < 4; r++) {
            int row = rbase + r;
            if (row < n)
                out[(size_t)row * F + col] = fmaxf(acc[nf][r] + bv, 0.f);
        }
    }
}

extern "C" void kernel_launch(void* const* d_in, const int* in_sizes, int n_in,
                              void* d_out, int out_size, void* d_ws, size_t ws_size,
                              hipStream_t stream) {
    const float* feat = (const float*)d_in[0];
    const int*   src  = (const int*)d_in[1];
    const int*   dst  = (const int*)d_in[2];
    const float* W    = (const float*)d_in[3];
    const float* bias = (const float*)d_in[4];
    float* out = (float*)d_out;

    const int n = in_sizes[0] / F;   // 50000 (even)
    const int E = in_sizes[1];       // 600000
    const int nw = n >> 1;           // 25000
    const int nwb = (nw + 255) / 256;              // 98
    const int rsize = (n + RANGES - 1) / RANGES;   // 6250 (<= 6400)
    const int eps = (E + SLICES - 1) / SLICES;     // 9375

    char* p = (char*)d_ws;
    auto alloc = [&](size_t bytes) { char* r = p; p += (bytes + 255) & ~255ull; return r; };
    u32* row_start   = (u32*)alloc((size_t)(n + 1) * 4);
    int* bsum2       = (int*)alloc((size_t)nwb * GROUPS * 4);
    int* bsum        = (int*)alloc(256 * 4);
    u32* gout        = (u32*)alloc((size_t)GROUPS * nw * 4);   // packed group deg_out
    u32* gin         = (u32*)alloc((size_t)GROUPS * nw * 4);   // packed group deg_in
    int* eidx        = (int*)alloc((size_t)E * 4);
    u16* eRank       = (u16*)alloc((size_t)E * 2);
    u32* cursor_base = (u32*)alloc((size_t)SLICES * n * 4);    // 12.8 MB
    u32* xb          = (u32*)alloc((size_t)n * F * 2);         // bf16 feat*norm_src
    u32* rep         = (u32*)alloc((size_t)SLICES * 2 * nw * 4); // 12.8 MB slice hists
    u16* wsw         = (u16*)alloc(128 * 128 * 2);             // swizzled transposed bf16 W

    hist_kernel<<<RANGES * SLICES, 256, 0, stream>>>(src, dst, rep, eRank, E, n, rsize, eps);
    slicesum_kernel<<<nwb * GROUPS, 256, 0, stream>>>(rep, gout, gin, bsum2, nw);
    scan_bsum_kernel<<<1, 256, 0, stream>>>(bsum2, bsum, row_start, nwb, n);
    scan_final_kernel<<<nwb, 256, 0, stream>>>(gin, bsum, row_start, n, nw);
    prep_kernel<<<6706, 256, 0, stream>>>(rep, gin, row_start, cursor_base,
                                          (const float4*)feat, gout, (ushort4*)xb,
                                          W, wsw, n, nw, n * 32);
    place_kernel<<<(E + 255) / 256, 256, 0, stream>>>(src, dst, eRank, cursor_base, eidx, E, n, eps);
    gather_gemm_kernel<<<(n + BM - 1) / BM, 256, 0, stream>>>(xb, eidx, row_start, gin,
                                                              (const uint4*)wsw, bias, out, n, nw);
}

// Round 12
// 112.861 us; speedup vs baseline: 1.5622x; 1.5622x over previous
//
#include <hip/hip_runtime.h>
#include <hip/hip_bf16.h>

#define F 128
#define RANGES 8
#define SLICES 64
#define GROUPS 4
#define GSL 16   // slices per group

typedef unsigned int u32;
typedef unsigned short u16;
typedef __attribute__((ext_vector_type(8))) short short8;   // bf16x8 MFMA frag
typedef __attribute__((ext_vector_type(4))) float f32x4;    // MFMA acc

__device__ __forceinline__ u16 f2bf(float x) {
    u32 u = __float_as_uint(x);
    u32 r = u + 0x7fffu + ((u >> 16) & 1u);   // RNE
    return (u16)(r >> 16);
}

// ---------------- range-partitioned LDS histogram + per-edge rank, no global atomics ----------------
__global__ __launch_bounds__(256) void hist_kernel(const int* __restrict__ src,
                                                   const int* __restrict__ dst,
                                                   u32* __restrict__ rep,
                                                   u16* __restrict__ eRank,
                                                   int E, int n, int rsize, int eps) {
    int r = blockIdx.x & (RANGES - 1);
    int s = blockIdx.x / RANGES;
    int lo = r * rsize;
    int hi = lo + rsize; if (hi > n) hi = n;
    int len = hi - lo;                 // 6250
    int words = (len + 1) >> 1;        // 3125
    __shared__ u32 h0[3200], h1[3200]; // 25.6 KB total
    for (int i = threadIdx.x; i < 3200; i += 256) { h0[i] = 0; h1[i] = 0; }
    __syncthreads();
    int e0 = s * eps, e1 = e0 + eps; if (e1 > E) e1 = E;
    for (int e = e0 + threadIdx.x; e < e1; e += 256) {
        int a = src[e] - lo;
        if ((u32)a < (u32)len) atomicAdd(&h0[a >> 1], 1u << ((a & 1) * 16));
        int b = dst[e] - lo;
        if ((u32)b < (u32)len) {
            int sh = (b & 1) * 16;
            u32 old = atomicAdd(&h1[b >> 1], 1u << sh);
            eRank[e] = (u16)((old >> sh) & 0xffffu);
        }
    }
    __syncthreads();
    int nw = n >> 1;
    u32* ro = rep + (size_t)s * 2 * nw + (lo >> 1);
    for (int i = threadIdx.x; i < words; i += 256) {
        ro[i]      = h0[i];
        ro[nw + i] = h1[i];
    }
}

// ---------------- per-group slice sums (packed) + per-(b,g) bsum partial (no atomics) ----------------
__global__ void slicesum_kernel(const u32* __restrict__ rep, u32* __restrict__ gout,
                                u32* __restrict__ gin, int* __restrict__ bsum2, int nw) {
    int b = blockIdx.x >> 2;
    int g = blockIdx.x & 3;
    int t = threadIdx.x;
    int j = b * 256 + t;
    u32 so = 0, si = 0;
    if (j < nw) {
        const u32* base = rep + (size_t)(g * GSL) * 2 * nw;
        #pragma unroll 4
        for (int s = 0; s < GSL; s++) {
            so += base[(size_t)s * 2 * nw + j];
            si += base[(size_t)s * 2 * nw + nw + j];
        }
        gout[g * nw + j] = so;
        gin [g * nw + j] = si;
    }
    int tot = (int)(si & 0xffffu) + (int)(si >> 16);
    for (int off = 32; off > 0; off >>= 1) tot += __shfl_down(tot, off, 64);
    __shared__ int ws[4];
    if ((t & 63) == 0) ws[t >> 6] = tot;
    __syncthreads();
    if (t == 0) bsum2[b * GROUPS + g] = ws[0] + ws[1] + ws[2] + ws[3];
}

// ---------------- exclusive scan of block sums (nb <= 256), folds 4 group partials ----------------
__global__ void scan_bsum_kernel(const int* __restrict__ bsum2, int* __restrict__ bsum,
                                 u32* __restrict__ row_start, int nb, int n) {
    __shared__ int sh[256];
    int t = threadIdx.x;
    int x = 0;
    if (t < nb) {
        #pragma unroll
        for (int g = 0; g < GROUPS; g++) x += bsum2[t * GROUPS + g];
    }
    sh[t] = x;
    __syncthreads();
    for (int off = 1; off < 256; off <<= 1) {
        int y = (t >= off) ? sh[t - off] : 0;
        __syncthreads();
        sh[t] += y;
        __syncthreads();
    }
    if (t < nb) bsum[t] = sh[t] - x;
    if (t == 255) row_start[n] = (u32)sh[255];
}

// ---------------- full exclusive scan -> row_start ----------------
__global__ void scan_final_kernel(const u32* __restrict__ gin, const int* __restrict__ bsum,
                                  u32* __restrict__ row_start, int n, int nw) {
    int t = threadIdx.x, lane = t & 63, wid = t >> 6;
    int j = blockIdx.x * 256 + t;
    u32 v0 = 0, v1 = 0;
    if (j < nw) {
        #pragma unroll
        for (int g = 0; g < GROUPS; g++) {
            u32 w = gin[g * nw + j];
            v0 += w & 0xffffu; v1 += w >> 16;
        }
    }
    int sum2 = (int)(v0 + v1);
    int x = sum2;
    for (int off = 1; off < 64; off <<= 1) {
        int y = __shfl_up(x, off, 64);
        if (lane >= off) x += y;
    }
    int wex = x - sum2;
    __shared__ int wtot[4];
    if (lane == 63) wtot[wid] = x;
    __syncthreads();
    int wbase = 0;
    for (int w = 0; w < wid; w++) wbase += wtot[w];
    int base = bsum[blockIdx.x] + wbase + wex;
    if (j < nw) {
        uint2 rs; rs.x = (u32)base; rs.y = (u32)base + v0;
        *(uint2*)&row_start[2 * j] = rs;
    }
}

// ---------------- prep: cursorw (blocks 0..391) | xconv (392..6641) | wconv (6642..6705) ----------------
__global__ void prep_kernel(const u32* __restrict__ rep, const u32* __restrict__ gin,
                            const u32* __restrict__ row_start, u32* __restrict__ cursor_base,
                            const float4* __restrict__ feat4, const u32* __restrict__ gout,
                            ushort4* __restrict__ xb4,
                            const float* __restrict__ Wg, u16* __restrict__ wsw,
                            int n, int nw, int total) {
    int bid = blockIdx.x;
    int t = threadIdx.x;
    if (bid < 392) {
        // -------- cursorw --------
        int b = bid >> 2;
        int g = bid & 3;
        int j = b * 256 + t;
        if (j >= nw) return;
        int i0 = 2 * j;
        uint2 rs = *(const uint2*)&row_start[i0];
        u32 c0 = rs.x, c1 = rs.y;
        for (int gp = 0; gp < g; gp++) {
            u32 w = gin[gp * nw + j];
            c0 += w & 0xffffu; c1 += w >> 16;
        }
        const u32* rin = rep + (size_t)(g * GSL) * 2 * nw + nw;
        u32* cb = cursor_base + (size_t)(g * GSL) * n + i0;
        #pragma unroll 4
        for (int s = 0; s < GSL; s++) {
            uint2 cc; cc.x = c0; cc.y = c1;
            *(uint2*)cb = cc;
            u32 w = rin[(size_t)s * 2 * nw + j];
            c0 += w & 0xffffu; c1 += w >> 16;
            cb += n;
        }
    } else if (bid < 6642) {
        // -------- xconv --------
        int i = (bid - 392) * 256 + t;
        if (i >= total) return;
        int row = i >> 5;
        int j = row >> 1, sh = (row & 1) * 16;
        u32 dg = 0;
        #pragma unroll
        for (int g = 0; g < GROUPS; g++) dg += (gout[g * nw + j] >> sh) & 0xffffu;
        if (dg < 1u) dg = 1u;
        float ns = rsqrtf((float)dg);
        float4 v = feat4[i];
        ushort4 o;
        o.x = f2bf(v.x * ns); o.y = f2bf(v.y * ns);
        o.z = f2bf(v.z * ns); o.w = f2bf(v.w * ns);
        xb4[i] = o;
    } else {
        // -------- wconv --------
        int i = (bid - 6642) * 256 + t;   // 0..16383
        int k = i >> 7, col = i & 127;
        u16 h = f2bf(Wg[i]);
        wsw[col * 128 + 8 * ((k >> 3) ^ (col & 15)) + (k & 7)] = h;
    }
}

// ---------------- placement: fully deterministic, zero atomics ----------------
__global__ void place_kernel(const int* __restrict__ src, const int* __restrict__ dst,
                             const u16* __restrict__ eRank, const u32* __restrict__ cursor_base,
                             int* __restrict__ eidx, int E, int n, int eps) {
    int e = blockIdx.x * blockDim.x + threadIdx.x;
    if (e < E) {
        int d = dst[e];
        int s = e / eps;
        u32 pos = cursor_base[(size_t)s * n + d] + eRank[e];
        eidx[pos] = src[e];
    }
}

// ---------------- gather: aggb[d] = bf16( norm_dst[d] * sum xb[s] ) ----------------
// one wave per dst row; lane holds one u32 (2 bf16); 8-deep load pipeline
__global__ void gather_kernel(const u32* __restrict__ xb32, const int* __restrict__ eidx,
                              const u32* __restrict__ row_start, const u32* __restrict__ gin,
                              u32* __restrict__ aggb32, int n, int nw) {
    int d = blockIdx.x * (blockDim.x >> 6) + (threadIdx.x >> 6);
    if (d >= n) return;
    int lane = threadIdx.x & 63;
    int beg = (int)row_start[d], end = (int)row_start[d + 1];
    float ax = 0.f, ay = 0.f;
    int k = beg;
    for (; k + 8 <= end; k += 8) {
        u32 v[8];
        #pragma unroll
        for (int q = 0; q < 8; q++) {
            int sq = __builtin_amdgcn_readfirstlane(eidx[k + q]);
            v[q] = xb32[(size_t)sq * 64 + lane];
        }
        #pragma unroll
        for (int q = 0; q < 8; q++) {
            ax += __uint_as_float(v[q] << 16);
            ay += __uint_as_float(v[q] & 0xffff0000u);
        }
    }
    for (; k < end; k++) {
        int s0 = __builtin_amdgcn_readfirstlane(eidx[k]);
        u32 v0 = xb32[(size_t)s0 * 64 + lane];
        ax += __uint_as_float(v0 << 16);
        ay += __uint_as_float(v0 & 0xffff0000u);
    }
    int j = d >> 1, sh = (d & 1) * 16;
    u32 dg = 0;
    #pragma unroll
    for (int g = 0; g < GROUPS; g++) dg += (gin[g * nw + j] >> sh) & 0xffffu;
    if (dg < 1u) dg = 1u;
    float nd = rsqrtf((float)dg);
    u32 lo = (u32)f2bf(ax * nd);
    u32 hi = (u32)f2bf(ay * nd);
    aggb32[(size_t)d * 64 + lane] = lo | (hi << 16);
}

// ---------------- out = relu(aggb @ W + b), MFMA bf16 ----------------
#define BM 64
__launch_bounds__(256)
__global__ void gemm_kernel(const u32* __restrict__ aggb, const uint4* __restrict__ wsw4,
                            const float* __restrict__ bias, float* __restrict__ out, int n) {
    __shared__ uint4 WL[2048];   // 32 KB
    int t = threadIdx.x;
    for (int j = t; j < 2048; j += 256)
        WL[j] = wsw4[j];
    __syncthreads();

    int lane = t & 63;
    int wv = t >> 6;
    int g = lane >> 4;
    int c15 = lane & 15;

    int rowA = blockIdx.x * BM + wv * 16 + c15;
    if (rowA >= n) rowA = n - 1;
    const short8* arow = (const short8*)(aggb + (size_t)rowA * 64);

    f32x4 acc[8];
    #pragma unroll
    for (int nf = 0; nf < 8; nf++) acc[nf] = (f32x4){0.f, 0.f, 0.f, 0.f};

    #pragma unroll
    for (int kk = 0; kk < 4; kk++) {
        short8 a = arow[4 * kk + g];
        int sg = (4 * kk + g) ^ c15;
        #pragma unroll
        for (int nf = 0; nf < 8; nf++) {
            int col = c15 + 16 * nf;
            short8 b = ((const short8*)WL)[col * 16 + sg];
            acc[nf] = __builtin_amdgcn_mfma_f32_16x16x32_bf16(a, b, acc[nf], 0, 0, 0);
        }
    }

    int rbase = blockIdx.x * BM + wv * 16 + g * 4;
    #pragma unroll
    for (int nf = 0; nf < 8; nf++) {
        int col = c15 + 16 * nf;
        float bv = bias[col];
        #pragma unroll
        for (int r = 0; r < 4; r++) {
            int row = rbase + r;
            if (row < n)
                out[(size_t)row * F + col] = fmaxf(acc[nf][r] + bv, 0.f);
        }
    }
}

extern "C" void kernel_launch(void* const* d_in, const int* in_sizes, int n_in,
                              void* d_out, int out_size, void* d_ws, size_t ws_size,
                              hipStream_t stream) {
    const float* feat = (const float*)d_in[0];
    const int*   src  = (const int*)d_in[1];
    const int*   dst  = (const int*)d_in[2];
    const float* W    = (const float*)d_in[3];
    const float* bias = (const float*)d_in[4];
    float* out = (float*)d_out;

    const int n = in_sizes[0] / F;   // 50000 (even)
    const int E = in_sizes[1];       // 600000
    const int nw = n >> 1;           // 25000
    const int nwb = (nw + 255) / 256;              // 98
    const int rsize = (n + RANGES - 1) / RANGES;   // 6250 (<= 6400)
    const int eps = (E + SLICES - 1) / SLICES;     // 9375

    char* p = (char*)d_ws;
    auto alloc = [&](size_t bytes) { char* r = p; p += (bytes + 255) & ~255ull; return r; };
    u32* row_start   = (u32*)alloc((size_t)(n + 1) * 4);
    int* bsum2       = (int*)alloc((size_t)nwb * GROUPS * 4);
    int* bsum        = (int*)alloc(256 * 4);
    u32* gout        = (u32*)alloc((size_t)GROUPS * nw * 4);   // packed group deg_out
    u32* gin         = (u32*)alloc((size_t)GROUPS * nw * 4);   // packed group deg_in
    int* eidx        = (int*)alloc((size_t)E * 4);
    u16* eRank       = (u16*)alloc((size_t)E * 2);
    u32* cursor_base = (u32*)alloc((size_t)SLICES * n * 4);    // 12.8 MB
    u32* xb          = (u32*)alloc((size_t)n * F * 2);         // bf16 feat*norm_src
    u32* aggb        = (u32*)alloc((size_t)n * F * 2);         // bf16 aggregate
    u16* wsw         = (u16*)alloc(128 * 128 * 2);             // swizzled transposed bf16 W
    // rep aliases aggb (12.8MB each): rep last read by prep_kernel (cursorw part),
    // aggb first written by gather_kernel.
    u32* rep         = aggb;

    hist_kernel<<<RANGES * SLICES, 256, 0, stream>>>(src, dst, rep, eRank, E, n, rsize, eps);
    slicesum_kernel<<<nwb * GROUPS, 256, 0, stream>>>(rep, gout, gin, bsum2, nw);
    scan_bsum_kernel<<<1, 256, 0, stream>>>(bsum2, bsum, row_start, nwb, n);
    scan_final_kernel<<<nwb, 256, 0, stream>>>(gin, bsum, row_start, n, nw);
    prep_kernel<<<6706, 256, 0, stream>>>(rep, gin, row_start, cursor_base,
                                          (const float4*)feat, gout, (ushort4*)xb,
                                          W, wsw, n, nw, n * 32);
    place_kernel<<<(E + 255) / 256, 256, 0, stream>>>(src, dst, eRank, cursor_base, eidx, E, n, eps);
    gather_kernel<<<(n + 3) / 4, 256, 0, stream>>>(xb, eidx, row_start, gin, aggb, n, nw);
    gemm_kernel<<<(n + BM - 1) / BM, 256, 0, stream>>>(aggb, (const uint4*)wsw, bias, out, n);
}

// Round 13
// 107.326 us; speedup vs baseline: 1.6427x; 1.0516x over previous
//
#include <hip/hip_runtime.h>
#include <hip/hip_bf16.h>

#define F 128
#define RANGES 8
#define SLICES 64
#define GROUPS 4
#define GSL 16   // slices per group

typedef unsigned int u32;
typedef unsigned short u16;
typedef __attribute__((ext_vector_type(8))) short short8;   // bf16x8 MFMA frag
typedef __attribute__((ext_vector_type(4))) float f32x4;    // MFMA acc

__device__ __forceinline__ u16 f2bf(float x) {
    u32 u = __float_as_uint(x);
    u32 r = u + 0x7fffu + ((u >> 16) & 1u);   // RNE
    return (u16)(r >> 16);
}

// ---------------- range-partitioned LDS histogram + per-edge rank, no global atomics ----------------
__global__ __launch_bounds__(256) void hist_kernel(const int* __restrict__ src,
                                                   const int* __restrict__ dst,
                                                   u32* __restrict__ rep,
                                                   u16* __restrict__ eRank,
                                                   int E, int n, int rsize, int eps) {
    int r = blockIdx.x & (RANGES - 1);
    int s = blockIdx.x / RANGES;
    int lo = r * rsize;
    int hi = lo + rsize; if (hi > n) hi = n;
    int len = hi - lo;                 // 6250
    int words = (len + 1) >> 1;        // 3125
    __shared__ u32 h0[3200], h1[3200]; // 25.6 KB total
    for (int i = threadIdx.x; i < 3200; i += 256) { h0[i] = 0; h1[i] = 0; }
    __syncthreads();
    int e0 = s * eps, e1 = e0 + eps; if (e1 > E) e1 = E;
    for (int e = e0 + threadIdx.x; e < e1; e += 256) {
        int a = src[e] - lo;
        if ((u32)a < (u32)len) atomicAdd(&h0[a >> 1], 1u << ((a & 1) * 16));
        int b = dst[e] - lo;
        if ((u32)b < (u32)len) {
            int sh = (b & 1) * 16;
            u32 old = atomicAdd(&h1[b >> 1], 1u << sh);
            eRank[e] = (u16)((old >> sh) & 0xffffu);
        }
    }
    __syncthreads();
    int nw = n >> 1;
    u32* ro = rep + (size_t)s * 2 * nw + (lo >> 1);
    for (int i = threadIdx.x; i < words; i += 256) {
        ro[i]      = h0[i];
        ro[nw + i] = h1[i];
    }
}

// ---------------- per-group slice sums (packed) + per-(b,g) bsum partial (no atomics) ----------------
__global__ void slicesum_kernel(const u32* __restrict__ rep, u32* __restrict__ gout,
                                u32* __restrict__ gin, int* __restrict__ bsum2, int nw) {
    int b = blockIdx.x >> 2;
    int g = blockIdx.x & 3;
    int t = threadIdx.x;
    int j = b * 256 + t;
    u32 so = 0, si = 0;
    if (j < nw) {
        const u32* base = rep + (size_t)(g * GSL) * 2 * nw;
        #pragma unroll 4
        for (int s = 0; s < GSL; s++) {
            so += base[(size_t)s * 2 * nw + j];
            si += base[(size_t)s * 2 * nw + nw + j];
        }
        gout[g * nw + j] = so;
        gin [g * nw + j] = si;
    }
    int tot = (int)(si & 0xffffu) + (int)(si >> 16);
    for (int off = 32; off > 0; off >>= 1) tot += __shfl_down(tot, off, 64);
    __shared__ int ws[4];
    if ((t & 63) == 0) ws[t >> 6] = tot;
    __syncthreads();
    if (t == 0) bsum2[b * GROUPS + g] = ws[0] + ws[1] + ws[2] + ws[3];
}

// ---------------- full exclusive scan -> row_start; every block redundantly scans bsum2 ----------------
__global__ void scan_final_kernel(const u32* __restrict__ gin, const int* __restrict__ bsum2,
                                  u32* __restrict__ row_start, int n, int nw, int nwb) {
    __shared__ int sh[256];
    int t = threadIdx.x, lane = t & 63, wid = t >> 6;
    // fold 4 group partials per word-block, then scan (98 valid entries)
    int x0 = 0;
    if (t < nwb) {
        int4 b4 = *(const int4*)&bsum2[t * 4];
        x0 = b4.x + b4.y + b4.z + b4.w;
    }
    sh[t] = x0;
    __syncthreads();
    for (int off = 1; off < 256; off <<= 1) {
        int y = (t >= off) ? sh[t - off] : 0;
        __syncthreads();
        sh[t] += y;
        __syncthreads();
    }
    int blockBase = (blockIdx.x > 0) ? sh[blockIdx.x - 1] : 0;
    if (blockIdx.x == 0 && t == 0) row_start[n] = (u32)sh[nwb - 1];

    int j = blockIdx.x * 256 + t;
    u32 v0 = 0, v1 = 0;
    if (j < nw) {
        #pragma unroll
        for (int g = 0; g < GROUPS; g++) {
            u32 w = gin[g * nw + j];
            v0 += w & 0xffffu; v1 += w >> 16;
        }
    }
    int sum2 = (int)(v0 + v1);
    int x = sum2;
    for (int off = 1; off < 64; off <<= 1) {
        int y = __shfl_up(x, off, 64);
        if (lane >= off) x += y;
    }
    int wex = x - sum2;
    __shared__ int wtot[4];
    if (lane == 63) wtot[wid] = x;
    __syncthreads();
    int wbase = 0;
    for (int w = 0; w < wid; w++) wbase += wtot[w];
    int base = blockBase + wbase + wex;
    if (j < nw) {
        uint2 rs; rs.x = (u32)base; rs.y = (u32)base + v0;
        *(uint2*)&row_start[2 * j] = rs;
    }
}

// ---------------- prep: cursorw (blocks 0..391) | xconv (392..6641) | wconv (6642..6705) ----------------
__global__ void prep_kernel(const u32* __restrict__ rep, const u32* __restrict__ gin,
                            const u32* __restrict__ row_start, u32* __restrict__ cursor_base,
                            const float4* __restrict__ feat4, const u32* __restrict__ gout,
                            ushort4* __restrict__ xb4,
                            const float* __restrict__ Wg, u16* __restrict__ wsw,
                            int n, int nw, int total) {
    int bid = blockIdx.x;
    int t = threadIdx.x;
    if (bid < 392) {
        // -------- cursorw --------
        int b = bid >> 2;
        int g = bid & 3;
        int j = b * 256 + t;
        if (j >= nw) return;
        int i0 = 2 * j;
        uint2 rs = *(const uint2*)&row_start[i0];
        u32 c0 = rs.x, c1 = rs.y;
        for (int gp = 0; gp < g; gp++) {
            u32 w = gin[gp * nw + j];
            c0 += w & 0xffffu; c1 += w >> 16;
        }
        const u32* rin = rep + (size_t)(g * GSL) * 2 * nw + nw;
        u32* cb = cursor_base + (size_t)(g * GSL) * n + i0;
        #pragma unroll 4
        for (int s = 0; s < GSL; s++) {
            uint2 cc; cc.x = c0; cc.y = c1;
            *(uint2*)cb = cc;
            u32 w = rin[(size_t)s * 2 * nw + j];
            c0 += w & 0xffffu; c1 += w >> 16;
            cb += n;
        }
    } else if (bid < 6642) {
        // -------- xconv --------
        int i = (bid - 392) * 256 + t;
        if (i >= total) return;
        int row = i >> 5;
        int j = row >> 1, sh = (row & 1) * 16;
        u32 dg = 0;
        #pragma unroll
        for (int g = 0; g < GROUPS; g++) dg += (gout[g * nw + j] >> sh) & 0xffffu;
        if (dg < 1u) dg = 1u;
        float ns = rsqrtf((float)dg);
        float4 v = feat4[i];
        ushort4 o;
        o.x = f2bf(v.x * ns); o.y = f2bf(v.y * ns);
        o.z = f2bf(v.z * ns); o.w = f2bf(v.w * ns);
        xb4[i] = o;
    } else {
        // -------- wconv --------
        int i = (bid - 6642) * 256 + t;   // 0..16383
        int k = i >> 7, col = i & 127;
        u16 h = f2bf(Wg[i]);
        wsw[col * 128 + 8 * ((k >> 3) ^ (col & 15)) + (k & 7)] = h;
    }
}

// ---------------- placement: fully deterministic, zero atomics ----------------
__global__ void place_kernel(const int* __restrict__ src, const int* __restrict__ dst,
                             const u16* __restrict__ eRank, const u32* __restrict__ cursor_base,
                             int* __restrict__ eidx, int E, int n, int eps) {
    int e = blockIdx.x * blockDim.x + threadIdx.x;
    if (e < E) {
        int d = dst[e];
        int s = e / eps;
        u32 pos = cursor_base[(size_t)s * n + d] + eRank[e];
        eidx[pos] = src[e];
    }
}

// ---------------- gather: 2 edges/step, uint2 loads; halves merged via shfl_xor ----------------
// lane = half*32 + l32; half h processes edges k+h; l32 covers cols 4*l32..4*l32+3
__global__ void gather_kernel(const u32* __restrict__ xb32, const int* __restrict__ eidx,
                              const u32* __restrict__ row_start, const u32* __restrict__ gin,
                              u32* __restrict__ aggb32, int n, int nw) {
    int d = blockIdx.x * (blockDim.x >> 6) + (threadIdx.x >> 6);
    if (d >= n) return;
    int lane = threadIdx.x & 63;
    int half = lane >> 5;
    int l32 = lane & 31;
    const uint2* xb2 = (const uint2*)xb32;
    int beg = (int)row_start[d], end = (int)row_start[d + 1];
    float a0 = 0.f, a1 = 0.f, a2 = 0.f, a3 = 0.f;
    int k = beg;
    for (; k + 8 <= end; k += 8) {           // 4 pairs in flight
        uint2 v[4];
        #pragma unroll
        for (int i = 0; i < 4; i++) {
            int sA = __builtin_amdgcn_readfirstlane(eidx[k + 2 * i]);
            int sB = __builtin_amdgcn_readfirstlane(eidx[k + 2 * i + 1]);
            int sq = half ? sB : sA;
            v[i] = xb2[(size_t)sq * 32 + l32];
        }
        #pragma unroll
        for (int i = 0; i < 4; i++) {
            a0 += __uint_as_float(v[i].x << 16);
            a1 += __uint_as_float(v[i].x & 0xffff0000u);
            a2 += __uint_as_float(v[i].y << 16);
            a3 += __uint_as_float(v[i].y & 0xffff0000u);
        }
    }
    for (; k + 2 <= end; k += 2) {
        int sA = __builtin_amdgcn_readfirstlane(eidx[k]);
        int sB = __builtin_amdgcn_readfirstlane(eidx[k + 1]);
        int sq = half ? sB : sA;
        uint2 vv = xb2[(size_t)sq * 32 + l32];
        a0 += __uint_as_float(vv.x << 16);
        a1 += __uint_as_float(vv.x & 0xffff0000u);
        a2 += __uint_as_float(vv.y << 16);
        a3 += __uint_as_float(vv.y & 0xffff0000u);
    }
    if (k < end) {                            // odd leftover: half 0 only
        int sA = __builtin_amdgcn_readfirstlane(eidx[k]);
        if (half == 0) {
            uint2 vv = xb2[(size_t)sA * 32 + l32];
            a0 += __uint_as_float(vv.x << 16);
            a1 += __uint_as_float(vv.x & 0xffff0000u);
            a2 += __uint_as_float(vv.y << 16);
            a3 += __uint_as_float(vv.y & 0xffff0000u);
        }
    }
    a0 += __shfl_xor(a0, 32, 64);
    a1 += __shfl_xor(a1, 32, 64);
    a2 += __shfl_xor(a2, 32, 64);
    a3 += __shfl_xor(a3, 32, 64);

    int j = d >> 1, sh = (d & 1) * 16;
    u32 dg = 0;
    #pragma unroll
    for (int g = 0; g < GROUPS; g++) dg += (gin[g * nw + j] >> sh) & 0xffffu;
    if (dg < 1u) dg = 1u;
    float nd = rsqrtf((float)dg);
    if (half == 0) {
        uint2 o;
        o.x = (u32)f2bf(a0 * nd) | ((u32)f2bf(a1 * nd) << 16);
        o.y = (u32)f2bf(a2 * nd) | ((u32)f2bf(a3 * nd) << 16);
        ((uint2*)aggb32)[(size_t)d * 32 + l32] = o;
    }
}

// ---------------- out = relu(aggb @ W + b), MFMA bf16 ----------------
#define BM 64
__launch_bounds__(256)
__global__ void gemm_kernel(const u32* __restrict__ aggb, const uint4* __restrict__ wsw4,
                            const float* __restrict__ bias, float* __restrict__ out, int n) {
    __shared__ uint4 WL[2048];   // 32 KB
    int t = threadIdx.x;
    for (int j = t; j < 2048; j += 256)
        WL[j] = wsw4[j];
    __syncthreads();

    int lane = t & 63;
    int wv = t >> 6;
    int g = lane >> 4;
    int c15 = lane & 15;

    int rowA = blockIdx.x * BM + wv * 16 + c15;
    if (rowA >= n) rowA = n - 1;
    const short8* arow = (const short8*)(aggb + (size_t)rowA * 64);

    f32x4 acc[8];
    #pragma unroll
    for (int nf = 0; nf < 8; nf++) acc[nf] = (f32x4){0.f, 0.f, 0.f, 0.f};

    #pragma unroll
    for (int kk = 0; kk < 4; kk++) {
        short8 a = arow[4 * kk + g];
        int sg = (4 * kk + g) ^ c15;
        #pragma unroll
        for (int nf = 0; nf < 8; nf++) {
            int col = c15 + 16 * nf;
            short8 b = ((const short8*)WL)[col * 16 + sg];
            acc[nf] = __builtin_amdgcn_mfma_f32_16x16x32_bf16(a, b, acc[nf], 0, 0, 0);
        }
    }

    int rbase = blockIdx.x * BM + wv * 16 + g * 4;
    #pragma unroll
    for (int nf = 0; nf < 8; nf++) {
        int col = c15 + 16 * nf;
        float bv = bias[col];
        #pragma unroll
        for (int r = 0; r < 4; r++) {
            int row = rbase + r;
            if (row < n)
                out[(size_t)row * F + col] = fmaxf(acc[nf][r] + bv, 0.f);
        }
    }
}

extern "C" void kernel_launch(void* const* d_in, const int* in_sizes, int n_in,
                              void* d_out, int out_size, void* d_ws, size_t ws_size,
                              hipStream_t stream) {
    const float* feat = (const float*)d_in[0];
    const int*   src  = (const int*)d_in[1];
    const int*   dst  = (const int*)d_in[2];
    const float* W    = (const float*)d_in[3];
    const float* bias = (const float*)d_in[4];
    float* out = (float*)d_out;

    const int n = in_sizes[0] / F;   // 50000 (even)
    const int E = in_sizes[1];       // 600000
    const int nw = n >> 1;           // 25000
    const int nwb = (nw + 255) / 256;              // 98
    const int rsize = (n + RANGES - 1) / RANGES;   // 6250 (<= 6400)
    const int eps = (E + SLICES - 1) / SLICES;     // 9375

    char* p = (char*)d_ws;
    auto alloc = [&](size_t bytes) { char* r = p; p += (bytes + 255) & ~255ull; return r; };
    u32* row_start   = (u32*)alloc((size_t)(n + 1) * 4);
    int* bsum2       = (int*)alloc((size_t)nwb * GROUPS * 4);
    u32* gout        = (u32*)alloc((size_t)GROUPS * nw * 4);   // packed group deg_out
    u32* gin         = (u32*)alloc((size_t)GROUPS * nw * 4);   // packed group deg_in
    int* eidx        = (int*)alloc((size_t)E * 4);
    u16* eRank       = (u16*)alloc((size_t)E * 2);
    u32* cursor_base = (u32*)alloc((size_t)SLICES * n * 4);    // 12.8 MB
    u32* xb          = (u32*)alloc((size_t)n * F * 2);         // bf16 feat*norm_src
    u32* aggb        = (u32*)alloc((size_t)n * F * 2);         // bf16 aggregate
    u16* wsw         = (u16*)alloc(128 * 128 * 2);             // swizzled transposed bf16 W
    // rep aliases aggb (12.8MB each): rep last read by prep_kernel (cursorw part),
    // aggb first written by gather_kernel.
    u32* rep         = aggb;

    hist_kernel<<<RANGES * SLICES, 256, 0, stream>>>(src, dst, rep, eRank, E, n, rsize, eps);
    slicesum_kernel<<<nwb * GROUPS, 256, 0, stream>>>(rep, gout, gin, bsum2, nw);
    scan_final_kernel<<<nwb, 256, 0, stream>>>(gin, bsum2, row_start, n, nw, nwb);
    prep_kernel<<<6706, 256, 0, stream>>>(rep, gin, row_start, cursor_base,
                                          (const float4*)feat, gout, (ushort4*)xb,
                                          W, wsw, n, nw, n * 32);
    place_kernel<<<(E + 255) / 256, 256, 0, stream>>>(src, dst, eRank, cursor_base, eidx, E, n, eps);
    gather_kernel<<<(n + 3) / 4, 256, 0, stream>>>(xb, eidx, row_start, gin, aggb, n, nw);
    gemm_kernel<<<(n + BM - 1) / BM, 256, 0, stream>>>(aggb, (const uint4*)wsw, bias, out, n);
}

// Round 15
// 104.489 us; speedup vs baseline: 1.6873x; 1.0271x over previous
//
#include <hip/hip_runtime.h>
#include <hip/hip_bf16.h>

#define F 128
#define RANGES 8
#define SLICES 64
#define GROUPS 4
#define GSL 16   // slices per group

typedef unsigned int u32;
typedef unsigned short u16;
typedef __attribute__((ext_vector_type(8))) short short8;   // bf16x8 MFMA frag
typedef __attribute__((ext_vector_type(4))) float f32x4;    // MFMA acc

__device__ __forceinline__ u16 f2bf(float x) {
    u32 u = __float_as_uint(x);
    u32 r = u + 0x7fffu + ((u >> 16) & 1u);   // RNE
    return (u16)(r >> 16);
}

// ---------------- range-partitioned LDS histogram + per-edge rank, no global atomics ----------------
__global__ __launch_bounds__(256) void hist_kernel(const int* __restrict__ src,
                                                   const int* __restrict__ dst,
                                                   u32* __restrict__ rep,
                                                   u16* __restrict__ eRank,
                                                   int E, int n, int rsize, int eps) {
    int r = blockIdx.x & (RANGES - 1);
    int s = blockIdx.x / RANGES;
    int lo = r * rsize;
    int hi = lo + rsize; if (hi > n) hi = n;
    int len = hi - lo;                 // 6250
    int words = (len + 1) >> 1;        // 3125
    __shared__ u32 h0[3200], h1[3200]; // 25.6 KB total
    for (int i = threadIdx.x; i < 3200; i += 256) { h0[i] = 0; h1[i] = 0; }
    __syncthreads();
    int e0 = s * eps, e1 = e0 + eps; if (e1 > E) e1 = E;
    for (int e = e0 + threadIdx.x; e < e1; e += 256) {
        int a = src[e] - lo;
        if ((u32)a < (u32)len) atomicAdd(&h0[a >> 1], 1u << ((a & 1) * 16));
        int b = dst[e] - lo;
        if ((u32)b < (u32)len) {
            int sh = (b & 1) * 16;
            u32 old = atomicAdd(&h1[b >> 1], 1u << sh);
            eRank[e] = (u16)((old >> sh) & 0xffffu);
        }
    }
    __syncthreads();
    int nw = n >> 1;
    u32* ro = rep + (size_t)s * 2 * nw + (lo >> 1);
    for (int i = threadIdx.x; i < words; i += 256) {
        ro[i]      = h0[i];
        ro[nw + i] = h1[i];
    }
}

// ---------------- per-group slice sums (packed) + per-(b,g) bsum partial (no atomics) ----------------
__global__ void slicesum_kernel(const u32* __restrict__ rep, u32* __restrict__ gout,
                                u32* __restrict__ gin, int* __restrict__ bsum2, int nw) {
    int b = blockIdx.x >> 2;
    int g = blockIdx.x & 3;
    int t = threadIdx.x;
    int j = b * 256 + t;
    u32 so = 0, si = 0;
    if (j < nw) {
        const u32* base = rep + (size_t)(g * GSL) * 2 * nw;
        #pragma unroll 4
        for (int s = 0; s < GSL; s++) {
            so += base[(size_t)s * 2 * nw + j];
            si += base[(size_t)s * 2 * nw + nw + j];
        }
        gout[g * nw + j] = so;
        gin [g * nw + j] = si;
    }
    int tot = (int)(si & 0xffffu) + (int)(si >> 16);
    for (int off = 32; off > 0; off >>= 1) tot += __shfl_down(tot, off, 64);
    __shared__ int ws[4];
    if ((t & 63) == 0) ws[t >> 6] = tot;
    __syncthreads();
    if (t == 0) bsum2[b * GROUPS + g] = ws[0] + ws[1] + ws[2] + ws[3];
}

// ---------------- full exclusive scan -> row_start; every block redundantly scans bsum2 ----------------
__global__ void scan_final_kernel(const u32* __restrict__ gin, const int* __restrict__ bsum2,
                                  u32* __restrict__ row_start, int n, int nw, int nwb) {
    __shared__ int sh[256];
    int t = threadIdx.x, lane = t & 63, wid = t >> 6;
    int x0 = 0;
    if (t < nwb) {
        int4 b4 = *(const int4*)&bsum2[t * 4];
        x0 = b4.x + b4.y + b4.z + b4.w;
    }
    sh[t] = x0;
    __syncthreads();
    for (int off = 1; off < 256; off <<= 1) {
        int y = (t >= off) ? sh[t - off] : 0;
        __syncthreads();
        sh[t] += y;
        __syncthreads();
    }
    int blockBase = (blockIdx.x > 0) ? sh[blockIdx.x - 1] : 0;
    if (blockIdx.x == 0 && t == 0) row_start[n] = (u32)sh[nwb - 1];

    int j = blockIdx.x * 256 + t;
    u32 v0 = 0, v1 = 0;
    if (j < nw) {
        #pragma unroll
        for (int g = 0; g < GROUPS; g++) {
            u32 w = gin[g * nw + j];
            v0 += w & 0xffffu; v1 += w >> 16;
        }
    }
    int sum2 = (int)(v0 + v1);
    int x = sum2;
    for (int off = 1; off < 64; off <<= 1) {
        int y = __shfl_up(x, off, 64);
        if (lane >= off) x += y;
    }
    int wex = x - sum2;
    __shared__ int wtot[4];
    if (lane == 63) wtot[wid] = x;
    __syncthreads();
    int wbase = 0;
    for (int w = 0; w < wid; w++) wbase += wtot[w];
    int base = blockBase + wbase + wex;
    if (j < nw) {
        uint2 rs; rs.x = (u32)base; rs.y = (u32)base + v0;
        *(uint2*)&row_start[2 * j] = rs;
    }
}

// ---------------- prep: cursorw (blocks 0..391) | xconv (392..6641) | wconv (6642..6705) ----------------
__global__ void prep_kernel(const u32* __restrict__ rep, const u32* __restrict__ gin,
                            const u32* __restrict__ row_start, u32* __restrict__ cursor_base,
                            const float4* __restrict__ feat4, const u32* __restrict__ gout,
                            ushort4* __restrict__ xb4,
                            const float* __restrict__ Wg, u16* __restrict__ wsw,
                            int n, int nw, int total) {
    int bid = blockIdx.x;
    int t = threadIdx.x;
    if (bid < 392) {
        // -------- cursorw --------
        int b = bid >> 2;
        int g = bid & 3;
        int j = b * 256 + t;
        if (j >= nw) return;
        int i0 = 2 * j;
        uint2 rs = *(const uint2*)&row_start[i0];
        u32 c0 = rs.x, c1 = rs.y;
        for (int gp = 0; gp < g; gp++) {
            u32 w = gin[gp * nw + j];
            c0 += w & 0xffffu; c1 += w >> 16;
        }
        const u32* rin = rep + (size_t)(g * GSL) * 2 * nw + nw;
        u32* cb = cursor_base + (size_t)(g * GSL) * n + i0;
        #pragma unroll 4
        for (int s = 0; s < GSL; s++) {
            uint2 cc; cc.x = c0; cc.y = c1;
            *(uint2*)cb = cc;
            u32 w = rin[(size_t)s * 2 * nw + j];
            c0 += w & 0xffffu; c1 += w >> 16;
            cb += n;
        }
    } else if (bid < 6642) {
        // -------- xconv --------
        int i = (bid - 392) * 256 + t;
        if (i >= total) return;
        int row = i >> 5;
        int j = row >> 1, sh = (row & 1) * 16;
        u32 dg = 0;
        #pragma unroll
        for (int g = 0; g < GROUPS; g++) dg += (gout[g * nw + j] >> sh) & 0xffffu;
        if (dg < 1u) dg = 1u;
        float ns = rsqrtf((float)dg);
        float4 v = feat4[i];
        ushort4 o;
        o.x = f2bf(v.x * ns); o.y = f2bf(v.y * ns);
        o.z = f2bf(v.z * ns); o.w = f2bf(v.w * ns);
        xb4[i] = o;
    } else {
        // -------- wconv --------
        int i = (bid - 6642) * 256 + t;   // 0..16383
        int k = i >> 7, col = i & 127;
        u16 h = f2bf(Wg[i]);
        wsw[col * 128 + 8 * ((k >> 3) ^ (col & 15)) + (k & 7)] = h;
    }
}

// ---------------- placement: fully deterministic, zero atomics ----------------
__global__ void place_kernel(const int* __restrict__ src, const int* __restrict__ dst,
                             const u16* __restrict__ eRank, const u32* __restrict__ cursor_base,
                             int* __restrict__ eidx, int E, int n, int eps) {
    int e = blockIdx.x * blockDim.x + threadIdx.x;
    if (e < E) {
        int d = dst[e];
        int s = e / eps;
        u32 pos = cursor_base[(size_t)s * n + d] + eRank[e];
        eidx[pos] = src[e];
    }
}

// ---------------- gather v3: 4 edges in parallel, uint4 (16B) loads, 16 lanes/row ----------------
// lane: q = lane>>4 selects edge k+q; l16 = lane&15 covers bytes l16*16 of the row.
// Quarter partials merged via shfl_xor(16) + shfl_xor(32); lanes 0..15 write the row.
__global__ void gather_kernel(const uint4* __restrict__ xb4, const int* __restrict__ eidx,
                              const u32* __restrict__ row_start, const u32* __restrict__ gin,
                              uint4* __restrict__ aggb4, int n, int nw) {
    int d = blockIdx.x * (blockDim.x >> 6) + (threadIdx.x >> 6);
    if (d >= n) return;
    int lane = threadIdx.x & 63;
    int q = lane >> 4;
    int l16 = lane & 15;
    int beg = (int)row_start[d], end = (int)row_start[d + 1];
    float a0 = 0.f, a1 = 0.f, a2 = 0.f, a3 = 0.f, a4 = 0.f, a5 = 0.f, a6 = 0.f, a7 = 0.f;
    int k = beg;
    for (; k + 8 <= end; k += 8) {          // 2 batches of 4 edges, 2 loads in flight
        int sA = eidx[k + q];
        int sB = eidx[k + 4 + q];
        uint4 vA = xb4[(size_t)sA * 16 + l16];
        uint4 vB = xb4[(size_t)sB * 16 + l16];
        a0 += __uint_as_float(vA.x << 16);  a1 += __uint_as_float(vA.x & 0xffff0000u);
        a2 += __uint_as_float(vA.y << 16);  a3 += __uint_as_float(vA.y & 0xffff0000u);
        a4 += __uint_as_float(vA.z << 16);  a5 += __uint_as_float(vA.z & 0xffff0000u);
        a6 += __uint_as_float(vA.w << 16);  a7 += __uint_as_float(vA.w & 0xffff0000u);
        a0 += __uint_as_float(vB.x << 16);  a1 += __uint_as_float(vB.x & 0xffff0000u);
        a2 += __uint_as_float(vB.y << 16);  a3 += __uint_as_float(vB.y & 0xffff0000u);
        a4 += __uint_as_float(vB.z << 16);  a5 += __uint_as_float(vB.z & 0xffff0000u);
        a6 += __uint_as_float(vB.w << 16);  a7 += __uint_as_float(vB.w & 0xffff0000u);
    }
    if (k + q < end) {                      // predicated tail (0..7 edges)
        int sA = eidx[k + q];
        uint4 vA = xb4[(size_t)sA * 16 + l16];
        a0 += __uint_as_float(vA.x << 16);  a1 += __uint_as_float(vA.x & 0xffff0000u);
        a2 += __uint_as_float(vA.y << 16);  a3 += __uint_as_float(vA.y & 0xffff0000u);
        a4 += __uint_as_float(vA.z << 16);  a5 += __uint_as_float(vA.z & 0xffff0000u);
        a6 += __uint_as_float(vA.w << 16);  a7 += __uint_as_float(vA.w & 0xffff0000u);
    }
    if (k + 4 + q < end) {
        int sB = eidx[k + 4 + q];
        uint4 vB = xb4[(size_t)sB * 16 + l16];
        a0 += __uint_as_float(vB.x << 16);  a1 += __uint_as_float(vB.x & 0xffff0000u);
        a2 += __uint_as_float(vB.y << 16);  a3 += __uint_as_float(vB.y & 0xffff0000u);
        a4 += __uint_as_float(vB.z << 16);  a5 += __uint_as_float(vB.z & 0xffff0000u);
        a6 += __uint_as_float(vB.w << 16);  a7 += __uint_as_float(vB.w & 0xffff0000u);
    }
    // merge quarters
    a0 += __shfl_xor(a0, 16, 64); a0 += __shfl_xor(a0, 32, 64);
    a1 += __shfl_xor(a1, 16, 64); a1 += __shfl_xor(a1, 32, 64);
    a2 += __shfl_xor(a2, 16, 64); a2 += __shfl_xor(a2, 32, 64);
    a3 += __shfl_xor(a3, 16, 64); a3 += __shfl_xor(a3, 32, 64);
    a4 += __shfl_xor(a4, 16, 64); a4 += __shfl_xor(a4, 32, 64);
    a5 += __shfl_xor(a5, 16, 64); a5 += __shfl_xor(a5, 32, 64);
    a6 += __shfl_xor(a6, 16, 64); a6 += __shfl_xor(a6, 32, 64);
    a7 += __shfl_xor(a7, 16, 64); a7 += __shfl_xor(a7, 32, 64);

    int j = d >> 1, sh = (d & 1) * 16;
    u32 dg = 0;
    #pragma unroll
    for (int g = 0; g < GROUPS; g++) dg += (gin[g * nw + j] >> sh) & 0xffffu;
    if (dg < 1u) dg = 1u;
    float nd = rsqrtf((float)dg);
    if (lane < 16) {
        uint4 o;
        o.x = (u32)f2bf(a0 * nd) | ((u32)f2bf(a1 * nd) << 16);
        o.y = (u32)f2bf(a2 * nd) | ((u32)f2bf(a3 * nd) << 16);
        o.z = (u32)f2bf(a4 * nd) | ((u32)f2bf(a5 * nd) << 16);
        o.w = (u32)f2bf(a6 * nd) | ((u32)f2bf(a7 * nd) << 16);
        aggb4[(size_t)d * 16 + l16] = o;
    }
}

// ---------------- out = relu(aggb @ W + b), MFMA bf16; A-frags prefetched before WL stage ----------------
#define BM 64
__launch_bounds__(256)
__global__ void gemm_kernel(const u32* __restrict__ aggb, const uint4* __restrict__ wsw4,
                            const float* __restrict__ bias, float* __restrict__ out, int n) {
    __shared__ uint4 WL[2048];   // 32 KB
    int t = threadIdx.x;
    int lane = t & 63;
    int wv = t >> 6;
    int g = lane >> 4;
    int c15 = lane & 15;

    int rowA = blockIdx.x * BM + wv * 16 + c15;
    if (rowA >= n) rowA = n - 1;
    const short8* arow = (const short8*)(aggb + (size_t)rowA * 64);
    short8 a4[4];
    #pragma unroll
    for (int kk = 0; kk < 4; kk++)
        a4[kk] = arow[4 * kk + g];          // issue global loads before LDS staging

    for (int j = t; j < 2048; j += 256)
        WL[j] = wsw4[j];
    __syncthreads();

    f32x4 acc[8];
    #pragma unroll
    for (int nf = 0; nf < 8; nf++) acc[nf] = (f32x4){0.f, 0.f, 0.f, 0.f};

    #pragma unroll
    for (int kk = 0; kk < 4; kk++) {
        int sg = (4 * kk + g) ^ c15;
        #pragma unroll
        for (int nf = 0; nf < 8; nf++) {
            int col = c15 + 16 * nf;
            short8 b = ((const short8*)WL)[col * 16 + sg];
            acc[nf] = __builtin_amdgcn_mfma_f32_16x16x32_bf16(a4[kk], b, acc[nf], 0, 0, 0);
        }
    }

    int rbase = blockIdx.x * BM + wv * 16 + g * 4;
    #pragma unroll
    for (int nf = 0; nf < 8; nf++) {
        int col = c15 + 16 * nf;
        float bv = bias[col];
        #pragma unroll
        for (int r = 0; r < 4; r++) {
            int row = rbase + r;
            if (row < n)
                out[(size_t)row * F + col] = fmaxf(acc[nf][r] + bv, 0.f);
        }
    }
}

extern "C" void kernel_launch(void* const* d_in, const int* in_sizes, int n_in,
                              void* d_out, int out_size, void* d_ws, size_t ws_size,
                              hipStream_t stream) {
    const float* feat = (const float*)d_in[0];
    const int*   src  = (const int*)d_in[1];
    const int*   dst  = (const int*)d_in[2];
    const float* W    = (const float*)d_in[3];
    const float* bias = (const float*)d_in[4];
    float* out = (float*)d_out;

    const int n = in_sizes[0] / F;   // 50000 (even)
    const int E = in_sizes[1];       // 600000
    const int nw = n >> 1;           // 25000
    const int nwb = (nw + 255) / 256;              // 98
    const int rsize = (n + RANGES - 1) / RANGES;   // 6250 (<= 6400)
    const int eps = (E + SLICES - 1) / SLICES;     // 9375

    char* p = (char*)d_ws;
    auto alloc = [&](size_t bytes) { char* r = p; p += (bytes + 255) & ~255ull; return r; };
    u32* row_start   = (u32*)alloc((size_t)(n + 1) * 4);
    int* bsum2       = (int*)alloc((size_t)nwb * GROUPS * 4);
    u32* gout        = (u32*)alloc((size_t)GROUPS * nw * 4);   // packed group deg_out
    u32* gin         = (u32*)alloc((size_t)GROUPS * nw * 4);   // packed group deg_in
    int* eidx        = (int*)alloc((size_t)E * 4);
    u16* eRank       = (u16*)alloc((size_t)E * 2);
    u32* cursor_base = (u32*)alloc((size_t)SLICES * n * 4);    // 12.8 MB
    u32* xb          = (u32*)alloc((size_t)n * F * 2);         // bf16 feat*norm_src
    u32* aggb        = (u32*)alloc((size_t)n * F * 2);         // bf16 aggregate
    u16* wsw         = (u16*)alloc(128 * 128 * 2);             // swizzled transposed bf16 W
    // rep aliases aggb (12.8MB each): rep last read by prep_kernel (cursorw part),
    // aggb first written by gather_kernel.
    u32* rep         = aggb;

    hist_kernel<<<RANGES * SLICES, 256, 0, stream>>>(src, dst, rep, eRank, E, n, rsize, eps);
    slicesum_kernel<<<nwb * GROUPS, 256, 0, stream>>>(rep, gout, gin, bsum2, nw);
    scan_final_kernel<<<nwb, 256, 0, stream>>>(gin, bsum2, row_start, n, nw, nwb);
    prep_kernel<<<6706, 256, 0, stream>>>(rep, gin, row_start, cursor_base,
                                          (const float4*)feat, gout, (ushort4*)xb,
                                          W, wsw, n, nw, n * 32);
    place_kernel<<<(E + 255) / 256, 256, 0, stream>>>(src, dst, eRank, cursor_base, eidx, E, n, eps);
    gather_kernel<<<(n + 3) / 4, 256, 0, stream>>>((const uint4*)xb, eidx, row_start, gin,
                                                   (uint4*)aggb, n, nw);
    gemm_kernel<<<(n + BM - 1) / BM, 256, 0, stream>>>(aggb, (const uint4*)wsw, bias, out, n);
}